// Round 10
// baseline (77.523 us; speedup 1.0000x reference)
//
#include <hip/hip_runtime.h>
#include <math.h>

#define DEV __device__ __forceinline__

struct F3 { float x, y, z; };

DEV F3 mkf3(float x, float y, float z){ F3 r; r.x=x; r.y=y; r.z=z; return r; }
DEV F3 f3add(F3 a, F3 b){ return mkf3(a.x+b.x, a.y+b.y, a.z+b.z); }
DEV F3 f3sub(F3 a, F3 b){ return mkf3(a.x-b.x, a.y-b.y, a.z-b.z); }
DEV F3 f3scale(F3 a, float s){ return mkf3(a.x*s, a.y*s, a.z*s); }
DEV float f3dot(F3 a, F3 b){ return a.x*b.x + a.y*b.y + a.z*b.z; }
DEV F3 f3cross(F3 a, F3 b){
  return mkf3(a.y*b.z - a.z*b.y, a.z*b.x - a.x*b.z, a.x*b.y - a.y*b.x);
}
// reference: v / sqrt(max(sum(v*v), 1e-6)); fallback branch is dead
DEV F3 f3dir(F3 v){
  float ss = f3dot(v, v);
  float inv = 1.0f / sqrtf(fmaxf(ss, 1e-6f));
  return f3scale(v, inv);
}
DEV float fast_silu(float x){
  return x * __builtin_amdgcn_rcpf(1.0f + __expf(-x));
}
DEV float fast_sigmoid(float x){
  return __builtin_amdgcn_rcpf(1.0f + __expf(-x));
}

// ---------------------------------------------------------------------------
// Kernel B: fused {frames + delta_local} + node MLP (2 layers + 3 heads),
// 4 rows/block. Block 0 threads 128-255 pack+prescale edge weights into wpk.
// ---------------------------------------------------------------------------
__global__ __launch_bounds__(256) void node_mlp(
    const float* __restrict__ h, const float* __restrict__ xc,
    const float* __restrict__ xt, const float* __restrict__ tau,
    const float* __restrict__ W1, const float* __restrict__ b1,
    const float* __restrict__ W2, const float* __restrict__ b2,
    const float* __restrict__ w_src, const float* __restrict__ b_src,
    const float* __restrict__ w_dst, const float* __restrict__ b_dst,
    const float* __restrict__ w_ns, const float* __restrict__ b_ns,
    const float* __restrict__ W_eg1, const float* __restrict__ b_eg1,
    const float* __restrict__ w_eg2,
    float* __restrict__ frames, float* __restrict__ dl,
    float* __restrict__ wpk,
    float* __restrict__ nh, float* __restrict__ srcv,
    float* __restrict__ dstv, float* __restrict__ nsv, int N)
{
  const int n0 = blockIdx.x * 4, tid = threadIdx.x;
  __shared__ float4 fA[262];       // [h, dl, t_emb] transposed, 4 rows
  __shared__ float4 fB[256];       // nh1 transposed, 4 rows
  __shared__ float red[4][4][3];   // [wave][row][head]
  __shared__ float sdl[4][3];

  // ---- weight pack (block 0, threads 128..255) ----
  if (blockIdx.x == 0 && tid >= 128) {
    int j = tid - 128;
    const float nl2e = -1.44269504088896340736f;  // -log2(e)
    const float nln2 = -0.69314718055994530942f;  // -ln(2)
    wpk[j*8+0] = nl2e * W_eg1[j];
    wpk[j*8+1] = nl2e * W_eg1[128 + j];
    wpk[j*8+2] = nl2e * W_eg1[256 + j];
    wpk[j*8+3] = nl2e * W_eg1[384 + j];
    wpk[j*8+4] = nl2e * b_eg1[j];
    wpk[j*8+5] = nln2 * w_eg2[j];
    wpk[j*8+6] = 0.f; wpk[j*8+7] = 0.f;
    if (j < 16) wpk[1024 + j] = 0.f;   // pad so prefetch overrun is benign
  }

  // ---- frames + delta_local for this block's 4 rows (threads 0..3) ----
  if (tid < 4) {
    int n = n0 + tid;
    int pn = (n > 0) ? n - 1 : 0;       // prev = d[max(n-1,0)]
    int qn = (n < N - 1) ? n : N - 2;   // nxt  = d[min(n,N-2)]
    F3 prev = mkf3(xc[(pn+1)*3+0]-xc[pn*3+0], xc[(pn+1)*3+1]-xc[pn*3+1], xc[(pn+1)*3+2]-xc[pn*3+2]);
    F3 nxt  = mkf3(xc[(qn+1)*3+0]-xc[qn*3+0], xc[(qn+1)*3+1]-xc[qn*3+1], xc[(qn+1)*3+2]-xc[qn*3+2]);

    F3 tangent = f3dir(f3add(prev, nxt));
    F3 curv    = f3dir(f3sub(nxt, prev));
    float ct   = f3dot(curv, tangent);
    F3 ay      = f3dir(f3sub(curv, f3scale(tangent, ct)));
    F3 az      = f3dir(f3cross(tangent, ay));
    ay         = f3dir(f3cross(az, tangent));

    float* fr = frames + n * 9;
    fr[0] = tangent.x; fr[1] = ay.x; fr[2] = az.x;
    fr[3] = tangent.y; fr[4] = ay.y; fr[5] = az.y;
    fr[6] = tangent.z; fr[7] = ay.z; fr[8] = az.z;

    F3 delta = mkf3(xt[n*3+0]-xc[n*3+0], xt[n*3+1]-xc[n*3+1], xt[n*3+2]-xc[n*3+2]);
    float d0 = f3dot(tangent, delta), d1 = f3dot(ay, delta), d2 = f3dot(az, delta);
    dl[n*3+0] = d0; dl[n*3+1] = d1; dl[n*3+2] = d2;
    sdl[tid][0] = d0; sdl[tid][1] = d1; sdl[tid][2] = d2;
  }
  __syncthreads();

  // ---- stage activations (transposed float4) ----
  {
    const float* hp = h + n0 * 256 + tid;
    fA[tid] = make_float4(hp[0], hp[256], hp[512], hp[768]);
  }
  if (tid < 6) {
    int k = 256 + tid;
    float4 v;
    if (tid < 3) {
      v = make_float4(sdl[0][tid], sdl[1][tid], sdl[2][tid], sdl[3][tid]);
    } else {
      float t = tau[0];
      float s = (tid == 3) ? t : ((tid == 4) ? sinf(t) : cosf(t));
      v = make_float4(s, s, s, s);
    }
    fA[k] = v;
  }
  __syncthreads();

  // ---- layer 1 ----
  {
    float bb = b1[tid];
    float a0 = bb, a1 = bb, a2 = bb, a3 = bb;
    const float* Wp = W1 + tid;
    for (int kb = 0; kb < 256; kb += 64) {
      float w[64];
      #pragma unroll
      for (int u = 0; u < 64; ++u) w[u] = Wp[(kb + u) * 256];
      #pragma unroll
      for (int u = 0; u < 64; ++u) {
        float4 f = fA[kb + u];
        a0 = fmaf(f.x, w[u], a0); a1 = fmaf(f.y, w[u], a1);
        a2 = fmaf(f.z, w[u], a2); a3 = fmaf(f.w, w[u], a3);
      }
    }
    #pragma unroll
    for (int k = 256; k < 262; ++k) {
      float w = Wp[k * 256];
      float4 f = fA[k];
      a0 = fmaf(f.x, w, a0); a1 = fmaf(f.y, w, a1);
      a2 = fmaf(f.z, w, a2); a3 = fmaf(f.w, w, a3);
    }
    fB[tid] = make_float4(fast_silu(a0), fast_silu(a1), fast_silu(a2), fast_silu(a3));
  }
  __syncthreads();

  // ---- layer 2 + heads ----
  float bb = b2[tid];
  float a0 = bb, a1 = bb, a2 = bb, a3 = bb;
  const float* Wp = W2 + tid;
  for (int kb = 0; kb < 256; kb += 64) {
    float w[64];
    #pragma unroll
    for (int u = 0; u < 64; ++u) w[u] = Wp[(kb + u) * 256];
    #pragma unroll
    for (int u = 0; u < 64; ++u) {
      float4 f = fB[kb + u];
      a0 = fmaf(f.x, w[u], a0); a1 = fmaf(f.y, w[u], a1);
      a2 = fmaf(f.z, w[u], a2); a3 = fmaf(f.w, w[u], a3);
    }
  }

  const float wsv = w_src[tid], wdv = w_dst[tid], wnv = w_ns[tid];
  const int wave = tid >> 6, lane = tid & 63;
  float va[4] = {fast_silu(a0), fast_silu(a1), fast_silu(a2), fast_silu(a3)};
  #pragma unroll
  for (int r = 0; r < 4; ++r) {
    nh[(n0 + r) * 256 + tid] = va[r];
    float ps = va[r] * wsv, pd = va[r] * wdv, pn = va[r] * wnv;
    for (int off = 32; off; off >>= 1) {
      ps += __shfl_down(ps, off);
      pd += __shfl_down(pd, off);
      pn += __shfl_down(pn, off);
    }
    if (lane == 0) { red[wave][r][0] = ps; red[wave][r][1] = pd; red[wave][r][2] = pn; }
  }
  __syncthreads();
  if (tid < 4) {
    int r = tid;
    float s0 = 0.f, s1 = 0.f, s2 = 0.f;
    #pragma unroll
    for (int w = 0; w < 4; ++w) { s0 += red[w][r][0]; s1 += red[w][r][1]; s2 += red[w][r][2]; }
    srcv[n0 + r] = s0 + b_src[0];
    dstv[n0 + r] = s1 + b_dst[0];
    nsv[n0 + r]  = fast_sigmoid(s2 + b_ns[0]);
  }
}

// ---------------------------------------------------------------------------
// Kernel D: fused edge MLP + softmax + aggregation, 2 ROWS per block.
// 256 thr, 4 waves; each thread owns 4 edges for BOTH rows (8 independent
// silu chains -> ILP hides the post-exp2 dependent chain; x_t/dst/ns loads
// and the uniform weight stream are shared between the rows).
// SiLU via poly-sigma, 1 trans/edge: xe = exp2(-|tp|) = exp(-|t|);
// g = xe*p2(xe) ~ 1-sigma(|t|); w2*silu(t) = w2' * min(tp-tp*g, tp*g).
// ---------------------------------------------------------------------------
__global__ __launch_bounds__(256, 2) void edge_softmax(
    const float* __restrict__ x_t, const float* __restrict__ frames,
    const float* __restrict__ srcv, const float* __restrict__ dstv,
    const float* __restrict__ nsv,
    const float* __restrict__ wpk, const float* __restrict__ b_eg2,
    float* __restrict__ msgs, int N)
{
  const int nA = blockIdx.x * 2, nB = nA + 1, tid = threadIdx.x;
  __shared__ float redmax[2][4];
  __shared__ float red[2][4][4];

  // row-uniform data -> scalar loads
  const float* fa = frames + nA * 9;
  const float* fb = frames + nB * 9;
  const float fA0=fa[0], fA1=fa[1], fA2=fa[2], fA3=fa[3], fA4=fa[4],
              fA5=fa[5], fA6=fa[6], fA7=fa[7], fA8=fa[8];
  const float fB0=fb[0], fB1=fb[1], fB2=fb[2], fB3=fb[3], fB4=fb[4],
              fB5=fb[5], fB6=fb[6], fB7=fb[7], fB8=fb[8];
  const float xA0 = x_t[nA*3+0], xA1 = x_t[nA*3+1], xA2 = x_t[nA*3+2];
  const float xB0 = x_t[nB*3+0], xB1 = x_t[nB*3+1], xB2 = x_t[nB*3+2];
  const float snA = srcv[nA] + b_eg2[0];
  const float snB = srcv[nB] + b_eg2[0];

  // ---- phase 0: rel_local + dist for 4 edges x 2 rows; shared dst/ns ----
  float dst_r[4], ns_r[4];
  float rA0[4], rA1[4], rA2[4], dA[4];
  float rB0[4], rB1[4], rB2[4], dB[4];
  #pragma unroll
  for (int e = 0; e < 4; ++e) {
    const int m = e * 256 + tid;
    dst_r[e] = dstv[m];
    ns_r[e]  = nsv[m];
    float mx = x_t[m*3+0], my = x_t[m*3+1], mz = x_t[m*3+2];
    float rx = mx - xA0, ry = my - xA1, rz = mz - xA2;
    rA0[e] = fA0*rx + fA3*ry + fA6*rz;
    rA1[e] = fA1*rx + fA4*ry + fA7*rz;
    rA2[e] = fA2*rx + fA5*ry + fA8*rz;
    dA[e]  = sqrtf(rA0[e]*rA0[e] + rA1[e]*rA1[e] + rA2[e]*rA2[e]);
    rx = mx - xB0; ry = my - xB1; rz = mz - xB2;
    rB0[e] = fB0*rx + fB3*ry + fB6*rz;
    rB1[e] = fB1*rx + fB4*ry + fB7*rz;
    rB2[e] = fB2*rx + fB5*ry + fB8*rz;
    dB[e]  = sqrtf(rB0[e]*rB0[e] + rB1[e]*rB1[e] + rB2[e]*rB2[e]);
  }

  // ---- phase 1: edge-MLP logits; poly-sigma, 1 trans/edge ----
  const float4* __restrict__ wp4 = (const float4*)wpk;
  // p2(x) ~ 1/(1+x) on [0,1], deg-2 minimax (x-weighted err ~8.6e-3)
  const float P0 = 0.991384f, P1 = -0.818352f, P2c = 0.333072f;
  float accA[4] = {0.f, 0.f, 0.f, 0.f};
  float accB[4] = {0.f, 0.f, 0.f, 0.f};

#define J_STEP(WA, WB)                                                  \
  {                                                                     \
    _Pragma("unroll")                                                   \
    for (int e = 0; e < 4; ++e) {                                       \
      float tpA = fmaf(WA.w, dA[e], WB.x);                              \
      tpA = fmaf(WA.z, rA2[e], tpA);                                    \
      tpA = fmaf(WA.y, rA1[e], tpA);                                    \
      tpA = fmaf(WA.x, rA0[e], tpA);                                    \
      float tpB = fmaf(WA.w, dB[e], WB.x);                              \
      tpB = fmaf(WA.z, rB2[e], tpB);                                    \
      tpB = fmaf(WA.y, rB1[e], tpB);                                    \
      tpB = fmaf(WA.x, rB0[e], tpB);                                    \
      float xeA = __builtin_amdgcn_exp2f(fminf(tpA, -tpA));             \
      float xeB = __builtin_amdgcn_exp2f(fminf(tpB, -tpB));             \
      float gA = fmaf(fmaf(P2c, xeA, P1), xeA, P0) * xeA;               \
      float gB = fmaf(fmaf(P2c, xeB, P1), xeB, P0) * xeB;               \
      float vA = tpA * gA, vB = tpB * gB;                               \
      float uA = tpA - vA, uB = tpB - vB;                               \
      accA[e] = fmaf(WB.y, fminf(uA, vA), accA[e]);                     \
      accB[e] = fmaf(WB.y, fminf(uB, vB), accB[e]);                     \
    }                                                                   \
  }

  // chunk = 2 j's (4 float4 uniform loads), prefetched one chunk ahead
  float4 ca0 = wp4[0], cb0 = wp4[1], ca1 = wp4[2], cb1 = wp4[3];
  for (int c = 0; c < 64; ++c) {
    float4 na0 = wp4[(c + 1) * 4 + 0];
    float4 nb0 = wp4[(c + 1) * 4 + 1];
    float4 na1 = wp4[(c + 1) * 4 + 2];
    float4 nb1 = wp4[(c + 1) * 4 + 3];
    J_STEP(ca0, cb0)
    J_STEP(ca1, cb1)
    ca0 = na0; cb0 = nb0; ca1 = na1; cb1 = nb1;
  }
#undef J_STEP

  const int wave = tid >> 6, lane = tid & 63;

  float lA[4], lB[4];
  float lmaxA = -3.4e38f, lmaxB = -3.4e38f;
  #pragma unroll
  for (int e = 0; e < 4; ++e) {
    const int m = e * 256 + tid;
    float lgA = snA + dst_r[e] + accA[e];
    float lgB = snB + dst_r[e] + accB[e];
    if (m == nA) lgA = -10000.0f;
    if (m == nB) lgB = -10000.0f;
    lA[e] = lgA; lB[e] = lgB;
    lmaxA = fmaxf(lmaxA, lgA);
    lmaxB = fmaxf(lmaxB, lgB);
  }

  // ---- block max reduce (both rows) ----
  for (int off = 32; off; off >>= 1) {
    lmaxA = fmaxf(lmaxA, __shfl_down(lmaxA, off));
    lmaxB = fmaxf(lmaxB, __shfl_down(lmaxB, off));
  }
  if (lane == 0) { redmax[0][wave] = lmaxA; redmax[1][wave] = lmaxB; }
  __syncthreads();
  const float mxA = fmaxf(fmaxf(redmax[0][0], redmax[0][1]), fmaxf(redmax[0][2], redmax[0][3]));
  const float mxB = fmaxf(fmaxf(redmax[1][0], redmax[1][1]), fmaxf(redmax[1][2], redmax[1][3]));

  // ---- phase 2: softmax + aggregation (both rows) ----
  float sA = 0.f, aA0 = 0.f, aA1 = 0.f, aA2 = 0.f;
  float sB = 0.f, aB0 = 0.f, aB1 = 0.f, aB2 = 0.f;
  #pragma unroll
  for (int e = 0; e < 4; ++e) {
    float eA = __expf(lA[e] - mxA);   // diag underflows to 0
    float eB = __expf(lB[e] - mxB);
    sA += eA; sB += eB;
    float wA = eA * ns_r[e], wB = eB * ns_r[e];
    aA0 = fmaf(wA, rA0[e], aA0); aA1 = fmaf(wA, rA1[e], aA1); aA2 = fmaf(wA, rA2[e], aA2);
    aB0 = fmaf(wB, rB0[e], aB0); aB1 = fmaf(wB, rB1[e], aB1); aB2 = fmaf(wB, rB2[e], aB2);
  }
  for (int off = 32; off; off >>= 1) {
    sA += __shfl_down(sA, off);
    aA0 += __shfl_down(aA0, off);
    aA1 += __shfl_down(aA1, off);
    aA2 += __shfl_down(aA2, off);
    sB += __shfl_down(sB, off);
    aB0 += __shfl_down(aB0, off);
    aB1 += __shfl_down(aB1, off);
    aB2 += __shfl_down(aB2, off);
  }
  if (lane == 0) {
    red[0][wave][0] = sA; red[0][wave][1] = aA0; red[0][wave][2] = aA1; red[0][wave][3] = aA2;
    red[1][wave][0] = sB; red[1][wave][1] = aB0; red[1][wave][2] = aB1; red[1][wave][3] = aB2;
  }
  __syncthreads();
  if (tid < 2) {
    int r = tid, n = (r == 0) ? nA : nB;
    float Z  = red[r][0][0] + red[r][1][0] + red[r][2][0] + red[r][3][0];
    float m0 = red[r][0][1] + red[r][1][1] + red[r][2][1] + red[r][3][1];
    float m1 = red[r][0][2] + red[r][1][2] + red[r][2][2] + red[r][3][2];
    float m2 = red[r][0][3] + red[r][1][3] + red[r][2][3] + red[r][3][3];
    float invZ = 1.0f / Z;
    msgs[n * 3 + 0] = m0 * invZ;
    msgs[n * 3 + 1] = m1 * invZ;
    msgs[n * 3 + 2] = m2 * invZ;
  }
}

// ---------------------------------------------------------------------------
// Kernel E: out MLP + 0.25*msgs + frame rotation  (4 rows/block)
// ---------------------------------------------------------------------------
__global__ __launch_bounds__(256) void out_mlp(
    const float* __restrict__ nh, const float* __restrict__ dl,
    const float* __restrict__ msgs, const float* __restrict__ frames,
    const float* __restrict__ W1, const float* __restrict__ b1,
    const float* __restrict__ W2, const float* __restrict__ b2,
    float* __restrict__ out, int N)
{
  const int n0 = blockIdx.x * 4, tid = threadIdx.x;
  __shared__ float4 feat4[262];
  __shared__ float red[4][4][3];
  {
    const float* hp = nh + n0 * 256 + tid;
    feat4[tid] = make_float4(hp[0], hp[256], hp[512], hp[768]);
  }
  if (tid < 6) {
    int k = 256 + tid;
    float4 v;
    if (tid < 3) {
      v = make_float4(dl[(n0+0)*3+tid], dl[(n0+1)*3+tid],
                      dl[(n0+2)*3+tid], dl[(n0+3)*3+tid]);
    } else {
      int c = tid - 3;
      v = make_float4(msgs[(n0+0)*3+c], msgs[(n0+1)*3+c],
                      msgs[(n0+2)*3+c], msgs[(n0+3)*3+c]);
    }
    feat4[k] = v;
  }
  __syncthreads();

  float bb = b1[tid];
  float a0 = bb, a1 = bb, a2 = bb, a3 = bb;
  const float* Wp = W1 + tid;
  for (int kb = 0; kb < 256; kb += 64) {
    float w[64];
    #pragma unroll
    for (int u = 0; u < 64; ++u) w[u] = Wp[(kb + u) * 256];
    #pragma unroll
    for (int u = 0; u < 64; ++u) {
      float4 f = feat4[kb + u];
      a0 = fmaf(f.x, w[u], a0); a1 = fmaf(f.y, w[u], a1);
      a2 = fmaf(f.z, w[u], a2); a3 = fmaf(f.w, w[u], a3);
    }
  }
  #pragma unroll
  for (int k = 256; k < 262; ++k) {
    float w = Wp[k * 256];
    float4 f = feat4[k];
    a0 = fmaf(f.x, w, a0); a1 = fmaf(f.y, w, a1);
    a2 = fmaf(f.z, w, a2); a3 = fmaf(f.w, w, a3);
  }

  const float w0 = W2[tid * 3 + 0], w1 = W2[tid * 3 + 1], w2 = W2[tid * 3 + 2];
  const int wave = tid >> 6, lane = tid & 63;
  float va[4] = {fast_silu(a0), fast_silu(a1), fast_silu(a2), fast_silu(a3)};
  #pragma unroll
  for (int r = 0; r < 4; ++r) {
    float p0 = va[r] * w0, p1 = va[r] * w1, p2 = va[r] * w2;
    for (int off = 32; off; off >>= 1) {
      p0 += __shfl_down(p0, off);
      p1 += __shfl_down(p1, off);
      p2 += __shfl_down(p2, off);
    }
    if (lane == 0) { red[wave][r][0] = p0; red[wave][r][1] = p1; red[wave][r][2] = p2; }
  }
  __syncthreads();
  if (tid < 4) {
    int r = tid, n = n0 + r;
    float s0 = 0.f, s1 = 0.f, s2 = 0.f;
    #pragma unroll
    for (int w = 0; w < 4; ++w) { s0 += red[w][r][0]; s1 += red[w][r][1]; s2 += red[w][r][2]; }
    float m0 = msgs[n * 3 + 0], m1 = msgs[n * 3 + 1], m2 = msgs[n * 3 + 2];
    float v0 = s0 + b2[0] + 0.25f * m0;
    float v1 = s1 + b2[1] + 0.25f * m1;
    float v2 = s2 + b2[2] + 0.25f * m2;
    const float* fr = frames + n * 9;
    out[n * 3 + 0] = fr[0] * v0 + fr[1] * v1 + fr[2] * v2;
    out[n * 3 + 1] = fr[3] * v0 + fr[4] * v1 + fr[5] * v2;
    out[n * 3 + 2] = fr[6] * v0 + fr[7] * v1 + fr[8] * v2;
  }
}

// ---------------------------------------------------------------------------
extern "C" void kernel_launch(void* const* d_in, const int* in_sizes, int n_in,
                              void* d_out, int out_size, void* d_ws, size_t ws_size,
                              hipStream_t stream) {
  const float* h      = (const float*)d_in[0];
  const float* x_t    = (const float*)d_in[1];
  const float* x_cond = (const float*)d_in[2];
  const float* tau    = (const float*)d_in[3];
  const float* W_np1  = (const float*)d_in[4];
  const float* b_np1  = (const float*)d_in[5];
  const float* W_np2  = (const float*)d_in[6];
  const float* b_np2  = (const float*)d_in[7];
  const float* w_src  = (const float*)d_in[8];
  const float* b_src  = (const float*)d_in[9];
  const float* w_dst  = (const float*)d_in[10];
  const float* b_dst  = (const float*)d_in[11];
  const float* w_ns   = (const float*)d_in[12];
  const float* b_ns   = (const float*)d_in[13];
  const float* W_eg1  = (const float*)d_in[14];
  const float* b_eg1  = (const float*)d_in[15];
  const float* w_eg2  = (const float*)d_in[16];
  const float* b_eg2  = (const float*)d_in[17];
  const float* W_out1 = (const float*)d_in[18];
  const float* b_out1 = (const float*)d_in[19];
  const float* W_out2 = (const float*)d_in[20];
  const float* b_out2 = (const float*)d_in[21];
  float* out = (float*)d_out;

  const int N = in_sizes[1] / 3;  // 1024

  float* ws     = (float*)d_ws;
  float* frames = ws;                 // N*9
  float* dl     = frames + N * 9;     // N*3
  float* nh     = dl + N * 3;         // N*256
  float* srcv   = nh + N * 256;       // N
  float* dstv   = srcv + N;           // N
  float* nsv    = dstv + N;           // N
  float* msgs   = nsv + N;            // N*3
  float* wpk    = msgs + N * 3;       // 128*8 + 16 pad

  node_mlp<<<N / 4, 256, 0, stream>>>(h, x_cond, x_t, tau,
                                      W_np1, b_np1, W_np2, b_np2,
                                      w_src, b_src, w_dst, b_dst, w_ns, b_ns,
                                      W_eg1, b_eg1, w_eg2,
                                      frames, dl, wpk,
                                      nh, srcv, dstv, nsv, N);
  edge_softmax<<<N / 2, 256, 0, stream>>>(x_t, frames, srcv, dstv, nsv,
                                          wpk, b_eg2, msgs, N);
  out_mlp<<<N / 4, 256, 0, stream>>>(nh, dl, msgs, frames,
                                     W_out1, b_out1, W_out2, b_out2, out, N);
}

// Round 11
// 69.744 us; speedup vs baseline: 1.1115x; 1.1115x over previous
//
#include <hip/hip_runtime.h>
#include <math.h>

#define DEV __device__ __forceinline__

typedef float v2f __attribute__((ext_vector_type(2)));
DEV v2f splat2(float s){ return (v2f){s, s}; }
DEV v2f pkfma(v2f a, v2f b, v2f c){ return __builtin_elementwise_fma(a, b, c); }

struct F3 { float x, y, z; };

DEV F3 mkf3(float x, float y, float z){ F3 r; r.x=x; r.y=y; r.z=z; return r; }
DEV F3 f3add(F3 a, F3 b){ return mkf3(a.x+b.x, a.y+b.y, a.z+b.z); }
DEV F3 f3sub(F3 a, F3 b){ return mkf3(a.x-b.x, a.y-b.y, a.z-b.z); }
DEV F3 f3scale(F3 a, float s){ return mkf3(a.x*s, a.y*s, a.z*s); }
DEV float f3dot(F3 a, F3 b){ return a.x*b.x + a.y*b.y + a.z*b.z; }
DEV F3 f3cross(F3 a, F3 b){
  return mkf3(a.y*b.z - a.z*b.y, a.z*b.x - a.x*b.z, a.x*b.y - a.y*b.x);
}
// reference: v / sqrt(max(sum(v*v), 1e-6)); fallback branch is dead
DEV F3 f3dir(F3 v){
  float ss = f3dot(v, v);
  float inv = 1.0f / sqrtf(fmaxf(ss, 1e-6f));
  return f3scale(v, inv);
}
DEV float fast_silu(float x){
  return x * __builtin_amdgcn_rcpf(1.0f + __expf(-x));
}
DEV float fast_sigmoid(float x){
  return __builtin_amdgcn_rcpf(1.0f + __expf(-x));
}

// ---------------------------------------------------------------------------
// Kernel B: fused {frames + delta_local} + node MLP (2 layers + 3 heads).
// 4 rows/block, ROW-PER-WAVE: wave r computes row n0+r; each thread owns
// 4 output cols -> float4 (dwordx4) weight loads, 32-deep register chunks.
// Block 0 threads 128-255 pack+prescale edge weights into wpk.
// ---------------------------------------------------------------------------
__global__ __launch_bounds__(256, 1) void node_mlp(
    const float* __restrict__ h, const float* __restrict__ xc,
    const float* __restrict__ xt, const float* __restrict__ tau,
    const float* __restrict__ W1, const float* __restrict__ b1,
    const float* __restrict__ W2, const float* __restrict__ b2,
    const float* __restrict__ w_src, const float* __restrict__ b_src,
    const float* __restrict__ w_dst, const float* __restrict__ b_dst,
    const float* __restrict__ w_ns, const float* __restrict__ b_ns,
    const float* __restrict__ W_eg1, const float* __restrict__ b_eg1,
    const float* __restrict__ w_eg2,
    float* __restrict__ frames, float* __restrict__ dl,
    float* __restrict__ wpk,
    float* __restrict__ nh, float* __restrict__ srcv,
    float* __restrict__ dstv, float* __restrict__ nsv, int N)
{
  const int n0 = blockIdx.x * 4, tid = threadIdx.x;
  const int row = tid >> 6, lane = tid & 63;
  const int c4 = lane << 2;
  const int n = n0 + row;

  __shared__ __align__(16) float feat[4][264];   // [h, dl, t_emb]
  __shared__ __align__(16) float fB[4][264];     // nh1
  __shared__ float sdl[4][3];

  // ---- weight pack (block 0, threads 128..255) ----
  if (blockIdx.x == 0 && tid >= 128) {
    int j = tid - 128;
    const float nl2e = -1.44269504088896340736f;  // -log2(e)
    const float nln2 = -0.69314718055994530942f;  // -ln(2)
    wpk[j*8+0] = nl2e * W_eg1[j];
    wpk[j*8+1] = nl2e * W_eg1[128 + j];
    wpk[j*8+2] = nl2e * W_eg1[256 + j];
    wpk[j*8+3] = nl2e * W_eg1[384 + j];
    wpk[j*8+4] = nl2e * b_eg1[j];
    wpk[j*8+5] = nln2 * w_eg2[j];
    wpk[j*8+6] = 0.f; wpk[j*8+7] = 0.f;
    if (j < 16) wpk[1024 + j] = 0.f;   // pad so prefetch overrun is benign
  }

  // ---- frames + delta_local for this block's 4 rows (threads 0..3) ----
  if (tid < 4) {
    int nn = n0 + tid;
    int pn = (nn > 0) ? nn - 1 : 0;       // prev = d[max(nn-1,0)]
    int qn = (nn < N - 1) ? nn : N - 2;   // nxt  = d[min(nn,N-2)]
    F3 prev = mkf3(xc[(pn+1)*3+0]-xc[pn*3+0], xc[(pn+1)*3+1]-xc[pn*3+1], xc[(pn+1)*3+2]-xc[pn*3+2]);
    F3 nxt  = mkf3(xc[(qn+1)*3+0]-xc[qn*3+0], xc[(qn+1)*3+1]-xc[qn*3+1], xc[(qn+1)*3+2]-xc[qn*3+2]);

    F3 tangent = f3dir(f3add(prev, nxt));
    F3 curv    = f3dir(f3sub(nxt, prev));
    float ct   = f3dot(curv, tangent);
    F3 ay      = f3dir(f3sub(curv, f3scale(tangent, ct)));
    F3 az      = f3dir(f3cross(tangent, ay));
    ay         = f3dir(f3cross(az, tangent));

    float* fr = frames + nn * 9;
    fr[0] = tangent.x; fr[1] = ay.x; fr[2] = az.x;
    fr[3] = tangent.y; fr[4] = ay.y; fr[5] = az.y;
    fr[6] = tangent.z; fr[7] = ay.z; fr[8] = az.z;

    F3 delta = mkf3(xt[nn*3+0]-xc[nn*3+0], xt[nn*3+1]-xc[nn*3+1], xt[nn*3+2]-xc[nn*3+2]);
    float d0 = f3dot(tangent, delta), d1 = f3dot(ay, delta), d2 = f3dot(az, delta);
    dl[nn*3+0] = d0; dl[nn*3+1] = d1; dl[nn*3+2] = d2;
    sdl[tid][0] = d0; sdl[tid][1] = d1; sdl[tid][2] = d2;
  }
  __syncthreads();

  // ---- stage features ----
  *(float4*)(&feat[row][c4]) = *(const float4*)(h + n * 256 + c4);
  if (lane == 0) {
    float t = tau[0];
    feat[row][256] = sdl[row][0];
    feat[row][257] = sdl[row][1];
    feat[row][258] = sdl[row][2];
    feat[row][259] = t;
    feat[row][260] = sinf(t);
    feat[row][261] = cosf(t);
    feat[row][262] = 0.f; feat[row][263] = 0.f;
  }
  __syncthreads();

  // ---- layer 1: thread computes cols c4..c4+3 of its row ----
  const float4* __restrict__ W1v = (const float4*)W1;
  float4 acc = *(const float4*)(b1 + c4);
  for (int kb = 0; kb < 256; kb += 32) {
    float4 w[32];
    #pragma unroll
    for (int u = 0; u < 32; ++u) w[u] = W1v[(kb + u) * 64 + lane];
    #pragma unroll
    for (int u = 0; u < 32; ++u) {
      float f = feat[row][kb + u];
      acc.x = fmaf(f, w[u].x, acc.x);
      acc.y = fmaf(f, w[u].y, acc.y);
      acc.z = fmaf(f, w[u].z, acc.z);
      acc.w = fmaf(f, w[u].w, acc.w);
    }
  }
  #pragma unroll
  for (int k = 256; k < 262; ++k) {
    float4 w = W1v[k * 64 + lane];
    float f = feat[row][k];
    acc.x = fmaf(f, w.x, acc.x);
    acc.y = fmaf(f, w.y, acc.y);
    acc.z = fmaf(f, w.z, acc.z);
    acc.w = fmaf(f, w.w, acc.w);
  }
  {
    float4 v1 = make_float4(fast_silu(acc.x), fast_silu(acc.y),
                            fast_silu(acc.z), fast_silu(acc.w));
    *(float4*)(&fB[row][c4]) = v1;
  }
  __syncthreads();

  // ---- layer 2 (K=256) ----
  const float4* __restrict__ W2v = (const float4*)W2;
  float4 a2 = *(const float4*)(b2 + c4);
  for (int kb = 0; kb < 256; kb += 32) {
    float4 w[32];
    #pragma unroll
    for (int u = 0; u < 32; ++u) w[u] = W2v[(kb + u) * 64 + lane];
    #pragma unroll
    for (int u = 0; u < 32; ++u) {
      float f = fB[row][kb + u];
      a2.x = fmaf(f, w[u].x, a2.x);
      a2.y = fmaf(f, w[u].y, a2.y);
      a2.z = fmaf(f, w[u].z, a2.z);
      a2.w = fmaf(f, w[u].w, a2.w);
    }
  }
  float4 va = make_float4(fast_silu(a2.x), fast_silu(a2.y),
                          fast_silu(a2.z), fast_silu(a2.w));
  *(float4*)(&nh[n * 256 + c4]) = va;

  // ---- heads: per-row single-wave reduction ----
  float4 ws4 = *(const float4*)(w_src + c4);
  float4 wd4 = *(const float4*)(w_dst + c4);
  float4 wn4 = *(const float4*)(w_ns + c4);
  float ps = va.x*ws4.x + va.y*ws4.y + va.z*ws4.z + va.w*ws4.w;
  float pd = va.x*wd4.x + va.y*wd4.y + va.z*wd4.z + va.w*wd4.w;
  float pn = va.x*wn4.x + va.y*wn4.y + va.z*wn4.z + va.w*wn4.w;
  for (int off = 32; off; off >>= 1) {
    ps += __shfl_down(ps, off);
    pd += __shfl_down(pd, off);
    pn += __shfl_down(pn, off);
  }
  if (lane == 0) {
    srcv[n] = ps + b_src[0];
    dstv[n] = pd + b_dst[0];
    nsv[n]  = fast_sigmoid(pn + b_ns[0]);
  }
}

// ---------------------------------------------------------------------------
// Kernel D: fused edge MLP + softmax + aggregation.  (EXACT round-7 version —
// best measured: 40.4-40.6 us, trans/issue-port bound.)
// One block (256 thr, 4 waves) per row n; 4 edges/thread as 2 v2f chains
// with explicit packed fma. Weights uniform (SGPR), pipelined 1 chunk ahead.
// ---------------------------------------------------------------------------
__global__ __launch_bounds__(256) void edge_softmax(
    const float* __restrict__ x_t, const float* __restrict__ frames,
    const float* __restrict__ srcv, const float* __restrict__ dstv,
    const float* __restrict__ nsv,
    const float* __restrict__ wpk, const float* __restrict__ b_eg2,
    float* __restrict__ msgs, int N)
{
  const int n = blockIdx.x, tid = threadIdx.x;
  __shared__ float redmax[4];
  __shared__ float red[4][4];

  // row-uniform data -> scalar loads
  const float f0 = frames[n*9+0], f1 = frames[n*9+1], f2 = frames[n*9+2],
              f3_ = frames[n*9+3], f4 = frames[n*9+4], f5 = frames[n*9+5],
              f6 = frames[n*9+6], f7 = frames[n*9+7], f8 = frames[n*9+8];
  const float x0 = x_t[n*3+0], x1 = x_t[n*3+1], x2 = x_t[n*3+2];
  const float sn = srcv[n];
  const float b2v = b_eg2[0];

  // ---- phase 0: 4 edges' rel_local + dist; prefetch dst/ns ----
  float r0s[4], r1s[4], r2s[4], dds[4], dst_r[4], ns_r[4];
  #pragma unroll
  for (int e = 0; e < 4; ++e) {
    const int m = e * 256 + tid;
    dst_r[e] = dstv[m];
    ns_r[e]  = nsv[m];
    float rx = x_t[m * 3 + 0] - x0;
    float ry = x_t[m * 3 + 1] - x1;
    float rz = x_t[m * 3 + 2] - x2;
    r0s[e] = f0 * rx + f3_ * ry + f6 * rz;
    r1s[e] = f1 * rx + f4 * ry + f7 * rz;
    r2s[e] = f2 * rx + f5 * ry + f8 * rz;
    dds[e] = sqrtf(r0s[e]*r0s[e] + r1s[e]*r1s[e] + r2s[e]*r2s[e]);
  }
  const v2f r0A = {r0s[0], r0s[1]}, r0B = {r0s[2], r0s[3]};
  const v2f r1A = {r1s[0], r1s[1]}, r1B = {r1s[2], r1s[3]};
  const v2f r2A = {r2s[0], r2s[1]}, r2B = {r2s[2], r2s[3]};
  const v2f ddA = {dds[0], dds[1]}, ddB = {dds[2], dds[3]};

  v2f accA = {0.f, 0.f}, accB = {0.f, 0.f};

  // ---- phase 1: edge-MLP logits; packed fma + pipelined uniform loads ----
  const float4* __restrict__ wp4 = (const float4*)wpk;

#define J_STEP(WA, WB)                                                        \
  {                                                                           \
    v2f wxx = splat2(WA.x), wyy = splat2(WA.y);                               \
    v2f wzz = splat2(WA.z), wdd = splat2(WA.w);                               \
    v2f wbb = splat2(WB.x), w22 = splat2(WB.y);                               \
    v2f tpA = pkfma(wdd, ddA, wbb);                                           \
    tpA = pkfma(wzz, r2A, tpA);                                               \
    tpA = pkfma(wyy, r1A, tpA);                                               \
    tpA = pkfma(wxx, r0A, tpA);                                               \
    v2f tpB = pkfma(wdd, ddB, wbb);                                           \
    tpB = pkfma(wzz, r2B, tpB);                                               \
    tpB = pkfma(wyy, r1B, tpB);                                               \
    tpB = pkfma(wxx, r0B, tpB);                                               \
    v2f eA, eB;                                                               \
    eA.x = __builtin_amdgcn_exp2f(tpA.x); eA.y = __builtin_amdgcn_exp2f(tpA.y); \
    eB.x = __builtin_amdgcn_exp2f(tpB.x); eB.y = __builtin_amdgcn_exp2f(tpB.y); \
    v2f opA = eA + splat2(1.0f);                                              \
    v2f opB = eB + splat2(1.0f);                                              \
    v2f sgA, sgB;                                                             \
    sgA.x = __builtin_amdgcn_rcpf(opA.x); sgA.y = __builtin_amdgcn_rcpf(opA.y); \
    sgB.x = __builtin_amdgcn_rcpf(opB.x); sgB.y = __builtin_amdgcn_rcpf(opB.y); \
    accA = pkfma(w22 * tpA, sgA, accA);                                       \
    accB = pkfma(w22 * tpB, sgB, accB);                                       \
  }

  // chunk = 2 j's (4 float4 uniform loads), prefetched one chunk ahead
  float4 ca0 = wp4[0], cb0 = wp4[1], ca1 = wp4[2], cb1 = wp4[3];
  for (int c = 0; c < 64; ++c) {
    float4 na0 = wp4[(c + 1) * 4 + 0];
    float4 nb0 = wp4[(c + 1) * 4 + 1];
    float4 na1 = wp4[(c + 1) * 4 + 2];
    float4 nb1 = wp4[(c + 1) * 4 + 3];
    J_STEP(ca0, cb0)
    J_STEP(ca1, cb1)
    ca0 = na0; cb0 = nb0; ca1 = na1; cb1 = nb1;
  }
#undef J_STEP

  float l[4];
  float lmax = -3.4e38f;
  float accs[4] = {accA.x, accA.y, accB.x, accB.y};
  #pragma unroll
  for (int e = 0; e < 4; ++e) {
    const int m = e * 256 + tid;
    float lg = sn + dst_r[e] + b2v + accs[e];
    if (m == n) lg = -10000.0f;
    l[e] = lg;
    lmax = fmaxf(lmax, lg);
  }

  // ---- block max reduce (4 waves) ----
  for (int off = 32; off; off >>= 1) lmax = fmaxf(lmax, __shfl_down(lmax, off));
  const int wave = tid >> 6, lane = tid & 63;
  if (lane == 0) redmax[wave] = lmax;
  __syncthreads();
  const float mx = fmaxf(fmaxf(redmax[0], redmax[1]), fmaxf(redmax[2], redmax[3]));

  // ---- phase 2: softmax + aggregation ----
  float r0all[4] = {r0A.x, r0A.y, r0B.x, r0B.y};
  float r1all[4] = {r1A.x, r1A.y, r1B.x, r1B.y};
  float r2all[4] = {r2A.x, r2A.y, r2B.x, r2B.y};
  float sum = 0.f, a0 = 0.f, a1 = 0.f, a2 = 0.f;
  #pragma unroll
  for (int e = 0; e < 4; ++e) {
    float ee = __expf(l[e] - mx);     // diag underflows to 0
    sum += ee;
    float w = ee * ns_r[e];
    a0 = fmaf(w, r0all[e], a0);
    a1 = fmaf(w, r1all[e], a1);
    a2 = fmaf(w, r2all[e], a2);
  }
  for (int off = 32; off; off >>= 1) {
    sum += __shfl_down(sum, off);
    a0 += __shfl_down(a0, off);
    a1 += __shfl_down(a1, off);
    a2 += __shfl_down(a2, off);
  }
  if (lane == 0) { red[wave][0] = sum; red[wave][1] = a0; red[wave][2] = a1; red[wave][3] = a2; }
  __syncthreads();
  if (tid == 0) {
    float Z  = red[0][0] + red[1][0] + red[2][0] + red[3][0];
    float m0 = red[0][1] + red[1][1] + red[2][1] + red[3][1];
    float m1 = red[0][2] + red[1][2] + red[2][2] + red[3][2];
    float m2 = red[0][3] + red[1][3] + red[2][3] + red[3][3];
    float invZ = 1.0f / Z;
    msgs[n * 3 + 0] = m0 * invZ;
    msgs[n * 3 + 1] = m1 * invZ;
    msgs[n * 3 + 2] = m2 * invZ;
  }
}

// ---------------------------------------------------------------------------
// Kernel E: out MLP + 0.25*msgs + frame rotation.
// 4 rows/block, row-per-wave, float4 weights (same scheme as node_mlp).
// ---------------------------------------------------------------------------
__global__ __launch_bounds__(256, 1) void out_mlp(
    const float* __restrict__ nh, const float* __restrict__ dl,
    const float* __restrict__ msgs, const float* __restrict__ frames,
    const float* __restrict__ W1, const float* __restrict__ b1,
    const float* __restrict__ W2, const float* __restrict__ b2,
    float* __restrict__ out, int N)
{
  const int n0 = blockIdx.x * 4, tid = threadIdx.x;
  const int row = tid >> 6, lane = tid & 63;
  const int c4 = lane << 2;
  const int n = n0 + row;

  __shared__ __align__(16) float feat[4][264];

  *(float4*)(&feat[row][c4]) = *(const float4*)(nh + n * 256 + c4);
  if (lane == 0) {
    feat[row][256] = dl[n*3+0];
    feat[row][257] = dl[n*3+1];
    feat[row][258] = dl[n*3+2];
    feat[row][259] = msgs[n*3+0];
    feat[row][260] = msgs[n*3+1];
    feat[row][261] = msgs[n*3+2];
    feat[row][262] = 0.f; feat[row][263] = 0.f;
  }
  __syncthreads();

  const float4* __restrict__ W1v = (const float4*)W1;
  float4 acc = *(const float4*)(b1 + c4);
  for (int kb = 0; kb < 256; kb += 32) {
    float4 w[32];
    #pragma unroll
    for (int u = 0; u < 32; ++u) w[u] = W1v[(kb + u) * 64 + lane];
    #pragma unroll
    for (int u = 0; u < 32; ++u) {
      float f = feat[row][kb + u];
      acc.x = fmaf(f, w[u].x, acc.x);
      acc.y = fmaf(f, w[u].y, acc.y);
      acc.z = fmaf(f, w[u].z, acc.z);
      acc.w = fmaf(f, w[u].w, acc.w);
    }
  }
  #pragma unroll
  for (int k = 256; k < 262; ++k) {
    float4 w = W1v[k * 64 + lane];
    float f = feat[row][k];
    acc.x = fmaf(f, w.x, acc.x);
    acc.y = fmaf(f, w.y, acc.y);
    acc.z = fmaf(f, w.z, acc.z);
    acc.w = fmaf(f, w.w, acc.w);
  }
  float4 hid = make_float4(fast_silu(acc.x), fast_silu(acc.y),
                           fast_silu(acc.z), fast_silu(acc.w));

  // ---- layer 2: W2 [256,3]; thread's 4 rows of W2 = 3 float4 loads ----
  const float4* __restrict__ W2v = (const float4*)W2;
  float4 q0 = W2v[lane * 3 + 0];   // {w[c4][0], w[c4][1], w[c4][2], w[c4+1][0]}
  float4 q1 = W2v[lane * 3 + 1];   // {w[c4+1][1], w[c4+1][2], w[c4+2][0], w[c4+2][1]}
  float4 q2 = W2v[lane * 3 + 2];   // {w[c4+2][2], w[c4+3][0], w[c4+3][1], w[c4+3][2]}
  float p0 = hid.x*q0.x + hid.y*q0.w + hid.z*q1.z + hid.w*q2.y;
  float p1 = hid.x*q0.y + hid.y*q1.x + hid.z*q1.w + hid.w*q2.z;
  float p2 = hid.x*q0.z + hid.y*q1.y + hid.z*q2.x + hid.w*q2.w;
  for (int off = 32; off; off >>= 1) {
    p0 += __shfl_down(p0, off);
    p1 += __shfl_down(p1, off);
    p2 += __shfl_down(p2, off);
  }
  if (lane == 0) {
    float v0 = p0 + b2[0] + 0.25f * feat[row][259];
    float v1 = p1 + b2[1] + 0.25f * feat[row][260];
    float v2 = p2 + b2[2] + 0.25f * feat[row][261];
    const float* fr = frames + n * 9;
    out[n * 3 + 0] = fr[0] * v0 + fr[1] * v1 + fr[2] * v2;
    out[n * 3 + 1] = fr[3] * v0 + fr[4] * v1 + fr[5] * v2;
    out[n * 3 + 2] = fr[6] * v0 + fr[7] * v1 + fr[8] * v2;
  }
}

// ---------------------------------------------------------------------------
extern "C" void kernel_launch(void* const* d_in, const int* in_sizes, int n_in,
                              void* d_out, int out_size, void* d_ws, size_t ws_size,
                              hipStream_t stream) {
  const float* h      = (const float*)d_in[0];
  const float* x_t    = (const float*)d_in[1];
  const float* x_cond = (const float*)d_in[2];
  const float* tau    = (const float*)d_in[3];
  const float* W_np1  = (const float*)d_in[4];
  const float* b_np1  = (const float*)d_in[5];
  const float* W_np2  = (const float*)d_in[6];
  const float* b_np2  = (const float*)d_in[7];
  const float* w_src  = (const float*)d_in[8];
  const float* b_src  = (const float*)d_in[9];
  const float* w_dst  = (const float*)d_in[10];
  const float* b_dst  = (const float*)d_in[11];
  const float* w_ns   = (const float*)d_in[12];
  const float* b_ns   = (const float*)d_in[13];
  const float* W_eg1  = (const float*)d_in[14];
  const float* b_eg1  = (const float*)d_in[15];
  const float* w_eg2  = (const float*)d_in[16];
  const float* b_eg2  = (const float*)d_in[17];
  const float* W_out1 = (const float*)d_in[18];
  const float* b_out1 = (const float*)d_in[19];
  const float* W_out2 = (const float*)d_in[20];
  const float* b_out2 = (const float*)d_in[21];
  float* out = (float*)d_out;

  const int N = in_sizes[1] / 3;  // 1024

  float* ws     = (float*)d_ws;
  float* frames = ws;                 // N*9
  float* dl     = frames + N * 9;     // N*3
  float* nh     = dl + N * 3;         // N*256
  float* srcv   = nh + N * 256;       // N
  float* dstv   = srcv + N;           // N
  float* nsv    = dstv + N;           // N
  float* msgs   = nsv + N;            // N*3
  float* wpk    = msgs + N * 3;       // 128*8 + 16 pad

  node_mlp<<<N / 4, 256, 0, stream>>>(h, x_cond, x_t, tau,
                                      W_np1, b_np1, W_np2, b_np2,
                                      w_src, b_src, w_dst, b_dst, w_ns, b_ns,
                                      W_eg1, b_eg1, w_eg2,
                                      frames, dl, wpk,
                                      nh, srcv, dstv, nsv, N);
  edge_softmax<<<N, 256, 0, stream>>>(x_t, frames, srcv, dstv, nsv,
                                      wpk, b_eg2, msgs, N);
  out_mlp<<<N / 4, 256, 0, stream>>>(nh, dl, msgs, frames,
                                     W_out1, b_out1, W_out2, b_out2, out, N);
}

// Round 12
// 61.925 us; speedup vs baseline: 1.2519x; 1.1263x over previous
//
#include <hip/hip_runtime.h>
#include <math.h>

#define DEV __device__ __forceinline__

typedef float v2f __attribute__((ext_vector_type(2)));
DEV v2f splat2(float s){ return (v2f){s, s}; }
DEV v2f pkfma(v2f a, v2f b, v2f c){ return __builtin_elementwise_fma(a, b, c); }

struct F3 { float x, y, z; };

DEV F3 mkf3(float x, float y, float z){ F3 r; r.x=x; r.y=y; r.z=z; return r; }
DEV F3 f3add(F3 a, F3 b){ return mkf3(a.x+b.x, a.y+b.y, a.z+b.z); }
DEV F3 f3sub(F3 a, F3 b){ return mkf3(a.x-b.x, a.y-b.y, a.z-b.z); }
DEV F3 f3scale(F3 a, float s){ return mkf3(a.x*s, a.y*s, a.z*s); }
DEV float f3dot(F3 a, F3 b){ return a.x*b.x + a.y*b.y + a.z*b.z; }
DEV F3 f3cross(F3 a, F3 b){
  return mkf3(a.y*b.z - a.z*b.y, a.z*b.x - a.x*b.z, a.x*b.y - a.y*b.x);
}
// reference: v / sqrt(max(sum(v*v), 1e-6)); fallback branch is dead
DEV F3 f3dir(F3 v){
  float ss = f3dot(v, v);
  float inv = 1.0f / sqrtf(fmaxf(ss, 1e-6f));
  return f3scale(v, inv);
}
DEV float fast_silu(float x){
  return x * __builtin_amdgcn_rcpf(1.0f + __expf(-x));
}
DEV float fast_sigmoid(float x){
  return __builtin_amdgcn_rcpf(1.0f + __expf(-x));
}

// ---------------------------------------------------------------------------
// Kernel B: fused {frames + delta_local} + node MLP (2 layers + 3 heads),
// 4 rows/block, col-per-thread, 64-deep scalar W prefetch (compiler keeps
// ~64 loads in flight — do NOT restructure; float4/row-per-wave variants
// regress to serial load-use, see r11).
// Block 0 threads 128-255 pack+prescale edge weights into wpk.
// ---------------------------------------------------------------------------
__global__ __launch_bounds__(256) void node_mlp(
    const float* __restrict__ h, const float* __restrict__ xc,
    const float* __restrict__ xt, const float* __restrict__ tau,
    const float* __restrict__ W1, const float* __restrict__ b1,
    const float* __restrict__ W2, const float* __restrict__ b2,
    const float* __restrict__ w_src, const float* __restrict__ b_src,
    const float* __restrict__ w_dst, const float* __restrict__ b_dst,
    const float* __restrict__ w_ns, const float* __restrict__ b_ns,
    const float* __restrict__ W_eg1, const float* __restrict__ b_eg1,
    const float* __restrict__ w_eg2,
    float* __restrict__ frames, float* __restrict__ dl,
    float* __restrict__ wpk,
    float* __restrict__ nh, float* __restrict__ srcv,
    float* __restrict__ dstv, float* __restrict__ nsv, int N)
{
  const int n0 = blockIdx.x * 4, tid = threadIdx.x;
  __shared__ float4 fA[262];       // [h, dl, t_emb] transposed, 4 rows
  __shared__ float4 fB[256];       // nh1 transposed, 4 rows
  __shared__ float red[4][4][3];   // [wave][row][head]
  __shared__ float sdl[4][3];

  // ---- weight pack (block 0, threads 128..255) ----
  if (blockIdx.x == 0 && tid >= 128) {
    int j = tid - 128;
    const float nl2e = -1.44269504088896340736f;  // -log2(e)
    const float nln2 = -0.69314718055994530942f;  // -ln(2)
    wpk[j*8+0] = nl2e * W_eg1[j];
    wpk[j*8+1] = nl2e * W_eg1[128 + j];
    wpk[j*8+2] = nl2e * W_eg1[256 + j];
    wpk[j*8+3] = nl2e * W_eg1[384 + j];
    wpk[j*8+4] = nl2e * b_eg1[j];
    wpk[j*8+5] = nln2 * w_eg2[j];
    wpk[j*8+6] = 0.f; wpk[j*8+7] = 0.f;
    if (j < 16) wpk[1024 + j] = 0.f;   // pad so prefetch overrun is benign
  }

  // ---- frames + delta_local for this block's 4 rows (threads 0..3) ----
  if (tid < 4) {
    int n = n0 + tid;
    int pn = (n > 0) ? n - 1 : 0;       // prev = d[max(n-1,0)]
    int qn = (n < N - 1) ? n : N - 2;   // nxt  = d[min(n,N-2)]
    F3 prev = mkf3(xc[(pn+1)*3+0]-xc[pn*3+0], xc[(pn+1)*3+1]-xc[pn*3+1], xc[(pn+1)*3+2]-xc[pn*3+2]);
    F3 nxt  = mkf3(xc[(qn+1)*3+0]-xc[qn*3+0], xc[(qn+1)*3+1]-xc[qn*3+1], xc[(qn+1)*3+2]-xc[qn*3+2]);

    F3 tangent = f3dir(f3add(prev, nxt));
    F3 curv    = f3dir(f3sub(nxt, prev));
    float ct   = f3dot(curv, tangent);
    F3 ay      = f3dir(f3sub(curv, f3scale(tangent, ct)));
    F3 az      = f3dir(f3cross(tangent, ay));
    ay         = f3dir(f3cross(az, tangent));

    float* fr = frames + n * 9;
    fr[0] = tangent.x; fr[1] = ay.x; fr[2] = az.x;
    fr[3] = tangent.y; fr[4] = ay.y; fr[5] = az.y;
    fr[6] = tangent.z; fr[7] = ay.z; fr[8] = az.z;

    F3 delta = mkf3(xt[n*3+0]-xc[n*3+0], xt[n*3+1]-xc[n*3+1], xt[n*3+2]-xc[n*3+2]);
    float d0 = f3dot(tangent, delta), d1 = f3dot(ay, delta), d2 = f3dot(az, delta);
    dl[n*3+0] = d0; dl[n*3+1] = d1; dl[n*3+2] = d2;
    sdl[tid][0] = d0; sdl[tid][1] = d1; sdl[tid][2] = d2;
  }
  __syncthreads();

  // ---- stage activations (transposed float4) ----
  {
    const float* hp = h + n0 * 256 + tid;
    fA[tid] = make_float4(hp[0], hp[256], hp[512], hp[768]);
  }
  if (tid < 6) {
    int k = 256 + tid;
    float4 v;
    if (tid < 3) {
      v = make_float4(sdl[0][tid], sdl[1][tid], sdl[2][tid], sdl[3][tid]);
    } else {
      float t = tau[0];
      float s = (tid == 3) ? t : ((tid == 4) ? sinf(t) : cosf(t));
      v = make_float4(s, s, s, s);
    }
    fA[k] = v;
  }
  __syncthreads();

  // ---- layer 1 ----
  {
    float bb = b1[tid];
    float a0 = bb, a1 = bb, a2 = bb, a3 = bb;
    const float* Wp = W1 + tid;
    for (int kb = 0; kb < 256; kb += 64) {
      float w[64];
      #pragma unroll
      for (int u = 0; u < 64; ++u) w[u] = Wp[(kb + u) * 256];
      #pragma unroll
      for (int u = 0; u < 64; ++u) {
        float4 f = fA[kb + u];
        a0 = fmaf(f.x, w[u], a0); a1 = fmaf(f.y, w[u], a1);
        a2 = fmaf(f.z, w[u], a2); a3 = fmaf(f.w, w[u], a3);
      }
    }
    #pragma unroll
    for (int k = 256; k < 262; ++k) {
      float w = Wp[k * 256];
      float4 f = fA[k];
      a0 = fmaf(f.x, w, a0); a1 = fmaf(f.y, w, a1);
      a2 = fmaf(f.z, w, a2); a3 = fmaf(f.w, w, a3);
    }
    fB[tid] = make_float4(fast_silu(a0), fast_silu(a1), fast_silu(a2), fast_silu(a3));
  }
  __syncthreads();

  // ---- layer 2 + heads ----
  float bb = b2[tid];
  float a0 = bb, a1 = bb, a2 = bb, a3 = bb;
  const float* Wp = W2 + tid;
  for (int kb = 0; kb < 256; kb += 64) {
    float w[64];
    #pragma unroll
    for (int u = 0; u < 64; ++u) w[u] = Wp[(kb + u) * 256];
    #pragma unroll
    for (int u = 0; u < 64; ++u) {
      float4 f = fB[kb + u];
      a0 = fmaf(f.x, w[u], a0); a1 = fmaf(f.y, w[u], a1);
      a2 = fmaf(f.z, w[u], a2); a3 = fmaf(f.w, w[u], a3);
    }
  }

  const float wsv = w_src[tid], wdv = w_dst[tid], wnv = w_ns[tid];
  const int wave = tid >> 6, lane = tid & 63;
  float va[4] = {fast_silu(a0), fast_silu(a1), fast_silu(a2), fast_silu(a3)};
  #pragma unroll
  for (int r = 0; r < 4; ++r) {
    nh[(n0 + r) * 256 + tid] = va[r];
    float ps = va[r] * wsv, pd = va[r] * wdv, pn = va[r] * wnv;
    for (int off = 32; off; off >>= 1) {
      ps += __shfl_down(ps, off);
      pd += __shfl_down(pd, off);
      pn += __shfl_down(pn, off);
    }
    if (lane == 0) { red[wave][r][0] = ps; red[wave][r][1] = pd; red[wave][r][2] = pn; }
  }
  __syncthreads();
  if (tid < 4) {
    int r = tid;
    float s0 = 0.f, s1 = 0.f, s2 = 0.f;
    #pragma unroll
    for (int w = 0; w < 4; ++w) { s0 += red[w][r][0]; s1 += red[w][r][1]; s2 += red[w][r][2]; }
    srcv[n0 + r] = s0 + b_src[0];
    dstv[n0 + r] = s1 + b_dst[0];
    nsv[n0 + r]  = fast_sigmoid(s2 + b_ns[0]);
  }
}

// ---------------------------------------------------------------------------
// Kernel D: fused edge MLP + softmax + aggregation.  (r7 form — best
// measured 40.4-40.6 us; at ~97% of the SIMD issue-port roofline for its
// mix: 28 VALU-issue + 8 trans x 16cy occupancy per wave-j.)
// One block (256 thr, 4 waves) per row n; 4 edges/thread as 2 v2f chains.
// Weights uniform (SGPR), software-pipelined 1 chunk (2 j) ahead.
// ---------------------------------------------------------------------------
__global__ __launch_bounds__(256) void edge_softmax(
    const float* __restrict__ x_t, const float* __restrict__ frames,
    const float* __restrict__ srcv, const float* __restrict__ dstv,
    const float* __restrict__ nsv,
    const float* __restrict__ wpk, const float* __restrict__ b_eg2,
    float* __restrict__ msgs, int N)
{
  const int n = blockIdx.x, tid = threadIdx.x;
  __shared__ float redmax[4];
  __shared__ float red[4][4];

  // row-uniform data -> scalar loads
  const float f0 = frames[n*9+0], f1 = frames[n*9+1], f2 = frames[n*9+2],
              f3_ = frames[n*9+3], f4 = frames[n*9+4], f5 = frames[n*9+5],
              f6 = frames[n*9+6], f7 = frames[n*9+7], f8 = frames[n*9+8];
  const float x0 = x_t[n*3+0], x1 = x_t[n*3+1], x2 = x_t[n*3+2];
  const float sn = srcv[n];
  const float b2v = b_eg2[0];

  // ---- phase 0: 4 edges' rel_local + dist; prefetch dst/ns ----
  float r0s[4], r1s[4], r2s[4], dds[4], dst_r[4], ns_r[4];
  #pragma unroll
  for (int e = 0; e < 4; ++e) {
    const int m = e * 256 + tid;
    dst_r[e] = dstv[m];
    ns_r[e]  = nsv[m];
    float rx = x_t[m * 3 + 0] - x0;
    float ry = x_t[m * 3 + 1] - x1;
    float rz = x_t[m * 3 + 2] - x2;
    r0s[e] = f0 * rx + f3_ * ry + f6 * rz;
    r1s[e] = f1 * rx + f4 * ry + f7 * rz;
    r2s[e] = f2 * rx + f5 * ry + f8 * rz;
    dds[e] = sqrtf(r0s[e]*r0s[e] + r1s[e]*r1s[e] + r2s[e]*r2s[e]);
  }
  const v2f r0A = {r0s[0], r0s[1]}, r0B = {r0s[2], r0s[3]};
  const v2f r1A = {r1s[0], r1s[1]}, r1B = {r1s[2], r1s[3]};
  const v2f r2A = {r2s[0], r2s[1]}, r2B = {r2s[2], r2s[3]};
  const v2f ddA = {dds[0], dds[1]}, ddB = {dds[2], dds[3]};

  v2f accA = {0.f, 0.f}, accB = {0.f, 0.f};

  // ---- phase 1: edge-MLP logits; pipelined uniform loads ----
  const float4* __restrict__ wp4 = (const float4*)wpk;

#define J_STEP(WA, WB)                                                        \
  {                                                                           \
    v2f wxx = splat2(WA.x), wyy = splat2(WA.y);                               \
    v2f wzz = splat2(WA.z), wdd = splat2(WA.w);                               \
    v2f wbb = splat2(WB.x), w22 = splat2(WB.y);                               \
    v2f tpA = pkfma(wdd, ddA, wbb);                                           \
    tpA = pkfma(wzz, r2A, tpA);                                               \
    tpA = pkfma(wyy, r1A, tpA);                                               \
    tpA = pkfma(wxx, r0A, tpA);                                               \
    v2f tpB = pkfma(wdd, ddB, wbb);                                           \
    tpB = pkfma(wzz, r2B, tpB);                                               \
    tpB = pkfma(wyy, r1B, tpB);                                               \
    tpB = pkfma(wxx, r0B, tpB);                                               \
    v2f eA, eB;                                                               \
    eA.x = __builtin_amdgcn_exp2f(tpA.x); eA.y = __builtin_amdgcn_exp2f(tpA.y); \
    eB.x = __builtin_amdgcn_exp2f(tpB.x); eB.y = __builtin_amdgcn_exp2f(tpB.y); \
    v2f opA = eA + splat2(1.0f);                                              \
    v2f opB = eB + splat2(1.0f);                                              \
    v2f sgA, sgB;                                                             \
    sgA.x = __builtin_amdgcn_rcpf(opA.x); sgA.y = __builtin_amdgcn_rcpf(opA.y); \
    sgB.x = __builtin_amdgcn_rcpf(opB.x); sgB.y = __builtin_amdgcn_rcpf(opB.y); \
    accA = pkfma(w22 * tpA, sgA, accA);                                       \
    accB = pkfma(w22 * tpB, sgB, accB);                                       \
  }

  // chunk = 2 j's (4 float4 uniform loads), prefetched one chunk ahead
  float4 ca0 = wp4[0], cb0 = wp4[1], ca1 = wp4[2], cb1 = wp4[3];
  for (int c = 0; c < 64; ++c) {
    float4 na0 = wp4[(c + 1) * 4 + 0];
    float4 nb0 = wp4[(c + 1) * 4 + 1];
    float4 na1 = wp4[(c + 1) * 4 + 2];
    float4 nb1 = wp4[(c + 1) * 4 + 3];
    J_STEP(ca0, cb0)
    J_STEP(ca1, cb1)
    ca0 = na0; cb0 = nb0; ca1 = na1; cb1 = nb1;
  }
#undef J_STEP

  float l[4];
  float lmax = -3.4e38f;
  float accs[4] = {accA.x, accA.y, accB.x, accB.y};
  #pragma unroll
  for (int e = 0; e < 4; ++e) {
    const int m = e * 256 + tid;
    float lg = sn + dst_r[e] + b2v + accs[e];
    if (m == n) lg = -10000.0f;
    l[e] = lg;
    lmax = fmaxf(lmax, lg);
  }

  // ---- block max reduce (4 waves) ----
  for (int off = 32; off; off >>= 1) lmax = fmaxf(lmax, __shfl_down(lmax, off));
  const int wave = tid >> 6, lane = tid & 63;
  if (lane == 0) redmax[wave] = lmax;
  __syncthreads();
  const float mx = fmaxf(fmaxf(redmax[0], redmax[1]), fmaxf(redmax[2], redmax[3]));

  // ---- phase 2: softmax + aggregation ----
  float r0all[4] = {r0A.x, r0A.y, r0B.x, r0B.y};
  float r1all[4] = {r1A.x, r1A.y, r1B.x, r1B.y};
  float r2all[4] = {r2A.x, r2A.y, r2B.x, r2B.y};
  float sum = 0.f, a0 = 0.f, a1 = 0.f, a2 = 0.f;
  #pragma unroll
  for (int e = 0; e < 4; ++e) {
    float ee = __expf(l[e] - mx);     // diag underflows to 0
    sum += ee;
    float w = ee * ns_r[e];
    a0 = fmaf(w, r0all[e], a0);
    a1 = fmaf(w, r1all[e], a1);
    a2 = fmaf(w, r2all[e], a2);
  }
  for (int off = 32; off; off >>= 1) {
    sum += __shfl_down(sum, off);
    a0 += __shfl_down(a0, off);
    a1 += __shfl_down(a1, off);
    a2 += __shfl_down(a2, off);
  }
  if (lane == 0) { red[wave][0] = sum; red[wave][1] = a0; red[wave][2] = a1; red[wave][3] = a2; }
  __syncthreads();
  if (tid == 0) {
    float Z  = red[0][0] + red[1][0] + red[2][0] + red[3][0];
    float m0 = red[0][1] + red[1][1] + red[2][1] + red[3][1];
    float m1 = red[0][2] + red[1][2] + red[2][2] + red[3][2];
    float m2 = red[0][3] + red[1][3] + red[2][3] + red[3][3];
    float invZ = 1.0f / Z;
    msgs[n * 3 + 0] = m0 * invZ;
    msgs[n * 3 + 1] = m1 * invZ;
    msgs[n * 3 + 2] = m2 * invZ;
  }
}

// ---------------------------------------------------------------------------
// Kernel E: out MLP + 0.25*msgs + frame rotation  (4 rows/block,
// col-per-thread, w[64] scalar prefetch — r7 form)
// ---------------------------------------------------------------------------
__global__ __launch_bounds__(256) void out_mlp(
    const float* __restrict__ nh, const float* __restrict__ dl,
    const float* __restrict__ msgs, const float* __restrict__ frames,
    const float* __restrict__ W1, const float* __restrict__ b1,
    const float* __restrict__ W2, const float* __restrict__ b2,
    float* __restrict__ out, int N)
{
  const int n0 = blockIdx.x * 4, tid = threadIdx.x;
  __shared__ float4 feat4[262];
  __shared__ float red[4][4][3];
  {
    const float* hp = nh + n0 * 256 + tid;
    feat4[tid] = make_float4(hp[0], hp[256], hp[512], hp[768]);
  }
  if (tid < 6) {
    int k = 256 + tid;
    float4 v;
    if (tid < 3) {
      v = make_float4(dl[(n0+0)*3+tid], dl[(n0+1)*3+tid],
                      dl[(n0+2)*3+tid], dl[(n0+3)*3+tid]);
    } else {
      int c = tid - 3;
      v = make_float4(msgs[(n0+0)*3+c], msgs[(n0+1)*3+c],
                      msgs[(n0+2)*3+c], msgs[(n0+3)*3+c]);
    }
    feat4[k] = v;
  }
  __syncthreads();

  float bb = b1[tid];
  float a0 = bb, a1 = bb, a2 = bb, a3 = bb;
  const float* Wp = W1 + tid;
  for (int kb = 0; kb < 256; kb += 64) {
    float w[64];
    #pragma unroll
    for (int u = 0; u < 64; ++u) w[u] = Wp[(kb + u) * 256];
    #pragma unroll
    for (int u = 0; u < 64; ++u) {
      float4 f = feat4[kb + u];
      a0 = fmaf(f.x, w[u], a0); a1 = fmaf(f.y, w[u], a1);
      a2 = fmaf(f.z, w[u], a2); a3 = fmaf(f.w, w[u], a3);
    }
  }
  #pragma unroll
  for (int k = 256; k < 262; ++k) {
    float w = Wp[k * 256];
    float4 f = feat4[k];
    a0 = fmaf(f.x, w, a0); a1 = fmaf(f.y, w, a1);
    a2 = fmaf(f.z, w, a2); a3 = fmaf(f.w, w, a3);
  }

  const float w0 = W2[tid * 3 + 0], w1 = W2[tid * 3 + 1], w2 = W2[tid * 3 + 2];
  const int wave = tid >> 6, lane = tid & 63;
  float va[4] = {fast_silu(a0), fast_silu(a1), fast_silu(a2), fast_silu(a3)};
  #pragma unroll
  for (int r = 0; r < 4; ++r) {
    float p0 = va[r] * w0, p1 = va[r] * w1, p2 = va[r] * w2;
    for (int off = 32; off; off >>= 1) {
      p0 += __shfl_down(p0, off);
      p1 += __shfl_down(p1, off);
      p2 += __shfl_down(p2, off);
    }
    if (lane == 0) { red[wave][r][0] = p0; red[wave][r][1] = p1; red[wave][r][2] = p2; }
  }
  __syncthreads();
  if (tid < 4) {
    int r = tid, n = n0 + r;
    float s0 = 0.f, s1 = 0.f, s2 = 0.f;
    #pragma unroll
    for (int w = 0; w < 4; ++w) { s0 += red[w][r][0]; s1 += red[w][r][1]; s2 += red[w][r][2]; }
    float m0 = msgs[n * 3 + 0], m1 = msgs[n * 3 + 1], m2 = msgs[n * 3 + 2];
    float v0 = s0 + b2[0] + 0.25f * m0;
    float v1 = s1 + b2[1] + 0.25f * m1;
    float v2 = s2 + b2[2] + 0.25f * m2;
    const float* fr = frames + n * 9;
    out[n * 3 + 0] = fr[0] * v0 + fr[1] * v1 + fr[2] * v2;
    out[n * 3 + 1] = fr[3] * v0 + fr[4] * v1 + fr[5] * v2;
    out[n * 3 + 2] = fr[6] * v0 + fr[7] * v1 + fr[8] * v2;
  }
}

// ---------------------------------------------------------------------------
extern "C" void kernel_launch(void* const* d_in, const int* in_sizes, int n_in,
                              void* d_out, int out_size, void* d_ws, size_t ws_size,
                              hipStream_t stream) {
  const float* h      = (const float*)d_in[0];
  const float* x_t    = (const float*)d_in[1];
  const float* x_cond = (const float*)d_in[2];
  const float* tau    = (const float*)d_in[3];
  const float* W_np1  = (const float*)d_in[4];
  const float* b_np1  = (const float*)d_in[5];
  const float* W_np2  = (const float*)d_in[6];
  const float* b_np2  = (const float*)d_in[7];
  const float* w_src  = (const float*)d_in[8];
  const float* b_src  = (const float*)d_in[9];
  const float* w_dst  = (const float*)d_in[10];
  const float* b_dst  = (const float*)d_in[11];
  const float* w_ns   = (const float*)d_in[12];
  const float* b_ns   = (const float*)d_in[13];
  const float* W_eg1  = (const float*)d_in[14];
  const float* b_eg1  = (const float*)d_in[15];
  const float* w_eg2  = (const float*)d_in[16];
  const float* b_eg2  = (const float*)d_in[17];
  const float* W_out1 = (const float*)d_in[18];
  const float* b_out1 = (const float*)d_in[19];
  const float* W_out2 = (const float*)d_in[20];
  const float* b_out2 = (const float*)d_in[21];
  float* out = (float*)d_out;

  const int N = in_sizes[1] / 3;  // 1024

  float* ws     = (float*)d_ws;
  float* frames = ws;                 // N*9
  float* dl     = frames + N * 9;     // N*3
  float* nh     = dl + N * 3;         // N*256
  float* srcv   = nh + N * 256;       // N
  float* dstv   = srcv + N;           // N
  float* nsv    = dstv + N;           // N
  float* msgs   = nsv + N;            // N*3
  float* wpk    = msgs + N * 3;       // 128*8 + 16 pad

  node_mlp<<<N / 4, 256, 0, stream>>>(h, x_cond, x_t, tau,
                                      W_np1, b_np1, W_np2, b_np2,
                                      w_src, b_src, w_dst, b_dst, w_ns, b_ns,
                                      W_eg1, b_eg1, w_eg2,
                                      frames, dl, wpk,
                                      nh, srcv, dstv, nsv, N);
  edge_softmax<<<N, 256, 0, stream>>>(x_t, frames, srcv, dstv, nsv,
                                      wpk, b_eg2, msgs, N);
  out_mlp<<<N / 4, 256, 0, stream>>>(nh, dl, msgs, frames,
                                     W_out1, b_out1, W_out2, b_out2, out, N);
}